// Round 1
// baseline (4329.154 us; speedup 1.0000x reference)
//
#include <hip/hip_runtime.h>
#include <math.h>

// Beam search (B=10, V=50257, D=1024, T=20) with RNN decoder.
// Per step: K1 per-beam partial top-10 + logsumexp partials over logits,
//           K2 merge + global select + output update (1 block),
//           K3 RNN step, K4 logits GEMM (h @ wo) into ws.
// Raw logits kept in ws; normalization via Z = logsumexp folded into K2.

#define BEAMS 10
#define VOCAB 50257
#define DIM   1024
#define TSTEPS 20
#define NBLK  16      // K1 blocks per beam
#define K1T   256     // K1 threads per block
#define NEGC  (-1e10f)

// ---------------------------------------------------------------- K1 --------
__global__ __launch_bounds__(K1T) void k_topk_partial(
    const float* __restrict__ logits,   // [BEAMS][VOCAB] raw
    float* __restrict__ pvals,          // [BEAMS*NBLK*10]
    int*   __restrict__ pidx,           // [BEAMS*NBLK*10]
    float* __restrict__ pmax,           // [BEAMS*NBLK]
    float* __restrict__ psum)           // [BEAMS*NBLK]
{
    const int beam = blockIdx.x / NBLK;
    const int blk  = blockIdx.x % NBLK;
    const int chunk = (VOCAB + NBLK - 1) / NBLK;     // 3142
    const int v0 = blk * chunk;
    const int v1 = (v0 + chunk < VOCAB) ? (v0 + chunk) : VOCAB;
    const float* row = logits + (size_t)beam * VOCAB;
    const int tid = threadIdx.x;

    // per-thread top-10 (static-indexed insertion network) + online logsumexp
    float tv[10]; int ti[10];
#pragma unroll
    for (int i = 0; i < 10; ++i) { tv[i] = -INFINITY; ti[i] = -1; }
    float tm = -INFINITY, ts = 0.f;

    for (int v = v0 + tid; v < v1; v += K1T) {
        float x = row[v];
        // logsumexp on RAW value (reference computes Z before UNK suppression)
        if (x > tm) { ts = ts * expf(tm - x) + 1.f; tm = x; }
        else        { ts += expf(x - tm); }
        float xs = (v == VOCAB - 1) ? x - 1000.f : x;   // UNK suppression
#pragma unroll
        for (int j = 9; j >= 1; --j) {
            if (xs > tv[j]) {
                bool shift = xs > tv[j - 1];
                tv[j] = shift ? tv[j - 1] : xs;
                ti[j] = shift ? ti[j - 1] : v;
            }
        }
        if (xs > tv[0]) { tv[0] = xs; ti[0] = v; }
    }

    __shared__ float s_v[K1T * 10];
    __shared__ int   s_i[K1T * 10];
    __shared__ float s_m[K1T];
    __shared__ float s_s[K1T];
    __shared__ float r_v[K1T];
    __shared__ int   r_j[K1T];

#pragma unroll
    for (int q = 0; q < 10; ++q) { s_v[tid * 10 + q] = tv[q]; s_i[tid * 10 + q] = ti[q]; }
    s_m[tid] = tm; s_s[tid] = ts;
    __syncthreads();

    // logsumexp tree reduce
    for (int off = K1T / 2; off; off >>= 1) {
        if (tid < off) {
            float m1 = s_m[tid], s1 = s_s[tid];
            float m2 = s_m[tid + off], s2 = s_s[tid + off];
            float m = fmaxf(m1, m2);
            float s = 0.f;
            if (m > -INFINITY) s = s1 * expf(m1 - m) + s2 * expf(m2 - m);
            s_m[tid] = m; s_s[tid] = s;
        }
        __syncthreads();
    }
    if (tid == 0) {
        pmax[beam * NBLK + blk] = s_m[0];
        psum[beam * NBLK + blk] = s_s[0];
    }

    // iterative extraction of block top-10 from the 2560 candidates
    for (int k = 0; k < 10; ++k) {
        float bv = -INFINITY; int bj = -1;
#pragma unroll
        for (int q = 0; q < 10; ++q) {
            float x = s_v[tid * 10 + q];
            if (x > bv) { bv = x; bj = tid * 10 + q; }
        }
        r_v[tid] = bv; r_j[tid] = bj;
        __syncthreads();
        if (tid < 64) {
            float v0r = r_v[tid]; int j0 = r_j[tid];
#pragma unroll
            for (int s = 1; s < K1T / 64; ++s) {
                float x = r_v[tid + s * 64];
                if (x > v0r) { v0r = x; j0 = r_j[tid + s * 64]; }
            }
#pragma unroll
            for (int off = 32; off; off >>= 1) {
                float ov = __shfl_xor(v0r, off);
                int   oj = __shfl_xor(j0, off);
                if (ov > v0r) { v0r = ov; j0 = oj; }
            }
            if (tid == 0) {
                pvals[(beam * NBLK + blk) * 10 + k] = v0r;
                pidx [(beam * NBLK + blk) * 10 + k] = s_i[j0];
                s_v[j0] = -INFINITY;
            }
        }
        __syncthreads();
    }
}

// ---------------------------------------------------------------- K2 --------
__global__ __launch_bounds__(640) void k_select_update(
    const float* __restrict__ pvals, const int* __restrict__ pidx,
    const float* __restrict__ pmax,  const float* __restrict__ psum,
    float* __restrict__ out,          // [0..199] seq, [200..399] lp, [400..409] sum
    int* __restrict__ toks, int* __restrict__ qsel, int t)
{
    __shared__ float s_mv[BEAMS][10];
    __shared__ int   s_mi[BEAMS][10];
    __shared__ float s_Z[BEAMS];
    __shared__ int   s_selq[10], s_seltok[10];
    __shared__ float s_selsum[10], s_sellocal[10];

    const int tid = threadIdx.x;
    const int w = tid >> 6, lane = tid & 63;

    if (w < BEAMS) {
        // merge NBLK partial top-10s of beam w (160 entries, 3 per lane)
        const float* pv = pvals + w * (NBLK * 10);
        const int*   pi = pidx  + w * (NBLK * 10);
        float mv0, mv1, mv2; int mi0, mi1, mi2;
        {
            int e0 = lane, e1 = lane + 64, e2 = lane + 128;
            mv0 = pv[e0]; mi0 = pi[e0];
            mv1 = (e1 < NBLK * 10) ? pv[e1] : -INFINITY; mi1 = (e1 < NBLK * 10) ? pi[e1] : -1;
            mv2 = (e2 < NBLK * 10) ? pv[e2] : -INFINITY; mi2 = (e2 < NBLK * 10) ? pi[e2] : -1;
        }
        for (int k = 0; k < 10; ++k) {
            float bv = mv0; int bs = 0;
            if (mv1 > bv) { bv = mv1; bs = 1; }
            if (mv2 > bv) { bv = mv2; bs = 2; }
            int meta = (lane << 2) | bs;
#pragma unroll
            for (int off = 32; off; off >>= 1) {
                float ov = __shfl_xor(bv, off);
                int   om = __shfl_xor(meta, off);
                if (ov > bv) { bv = ov; meta = om; }
            }
            int wl = meta >> 2, wslot = meta & 3;
            int cand_idx = (wslot == 0) ? mi0 : ((wslot == 1) ? mi1 : mi2);
            int widx = __shfl(cand_idx, wl);
            if (lane == 0) { s_mv[w][k] = bv; s_mi[w][k] = widx; }
            if (lane == wl) {
                if (wslot == 0) mv0 = -INFINITY;
                else if (wslot == 1) mv1 = -INFINITY;
                else mv2 = -INFINITY;
            }
        }
        // merge Z partials (lanes 0..15)
        float m = (lane < NBLK) ? pmax[w * NBLK + lane] : -INFINITY;
        float s = (lane < NBLK) ? psum[w * NBLK + lane] : 0.f;
#pragma unroll
        for (int off = NBLK / 2; off; off >>= 1) {
            float om = __shfl_xor(m, off);
            float os = __shfl_xor(s, off);
            float nm = fmaxf(m, om);
            s = s * expf(m - nm) + os * expf(om - nm);
            m = nm;
        }
        if (lane == 0) s_Z[w] = m + logf(s);
    }
    __syncthreads();

    // global select: top-10 of the 100 candidates (wave 0)
    if (w == 0) {
        float cv0, cv1;
        {
            int f = lane;   // slot 0
            if (f < 100) {
                int q = f / 10, c = f % 10;
                float val = s_mv[q][c] - s_Z[q];
                float bsum = (t == 0) ? 0.f : out[400 + q];
                float cand = bsum + val;
                if (t == 0 && q > 0) cand = NEGC;
                cv0 = cand;
            } else cv0 = -INFINITY;
            f = lane + 64;  // slot 1
            if (f < 100) {
                int q = f / 10, c = f % 10;
                float val = s_mv[q][c] - s_Z[q];
                float bsum = (t == 0) ? 0.f : out[400 + q];
                float cand = bsum + val;
                if (t == 0 && q > 0) cand = NEGC;
                cv1 = cand;
            } else cv1 = -INFINITY;
        }
        for (int k = 0; k < 10; ++k) {
            float bv = cv0; int bs = 0;
            if (cv1 > bv) { bv = cv1; bs = 1; }
            int meta = (lane << 1) | bs;
#pragma unroll
            for (int off = 32; off; off >>= 1) {
                float ov = __shfl_xor(bv, off);
                int   om = __shfl_xor(meta, off);
                if (ov > bv) { bv = ov; meta = om; }
            }
            int wl = meta >> 1, ws2 = meta & 1;
            int f = wl + ws2 * 64;
            int q = f / 10, c = f % 10;
            if (lane == 0) {
                s_selq[k]     = q;
                s_seltok[k]   = s_mi[q][c];
                s_selsum[k]   = bv;
                s_sellocal[k] = s_mv[q][c] - s_Z[q];
            }
            if (lane == wl) { if (ws2 == 0) cv0 = -INFINITY; else cv1 = -INFINITY; }
        }
    }
    __syncthreads();

    // update outputs: reorder prefix columns by q, append row t
    {
        int i = tid / 10, j = tid % 10;
        float vs = 0.f, vl = 0.f;
        if (tid < 200 && i < t) {
            int q = s_selq[j];
            vs = out[i * 10 + q];
            vl = out[200 + i * 10 + q];
        }
        __syncthreads();
        if (tid < 200) {
            if (i < t) {
                out[i * 10 + j] = vs;
                out[200 + i * 10 + j] = vl;
            } else if (i == t) {
                out[t * 10 + j] = (float)s_seltok[j];
                out[200 + t * 10 + j] = s_sellocal[j];
            }
        }
    }
    if (tid < 10) {
        int tk = s_seltok[tid];
        out[400 + tid] = (tk == 0) ? -1000.f : s_selsum[tid];
        toks[tid] = tk;
        qsel[tid] = s_selq[tid];
    }
}

// ---------------------------------------------------------------- K3 --------
__global__ __launch_bounds__(256) void k_rnn(
    const float* __restrict__ emb, const float* __restrict__ wx,
    const float* __restrict__ wh,  const float* __restrict__ hprev,
    const int* __restrict__ toks,  const int* __restrict__ qsel,
    float* __restrict__ hnext)
{
    const int b = blockIdx.x >> 2;                       // 0..9
    const int d = ((blockIdx.x & 3) << 8) + threadIdx.x; // 0..1023
    const float* ex = emb   + (size_t)toks[b] * DIM;     // wave-uniform -> s_load
    const float* hp = hprev + (size_t)qsel[b] * DIM;
    float acc = 0.f;
#pragma unroll 8
    for (int k = 0; k < DIM; ++k)
        acc = fmaf(ex[k], wx[(size_t)k * DIM + d], fmaf(hp[k], wh[(size_t)k * DIM + d], acc));
    hnext[b * DIM + d] = tanhf(acc);
}

// ---------------------------------------------------------------- K4 --------
__global__ __launch_bounds__(64) void k_logits(
    const float* __restrict__ h, const float* __restrict__ wo,
    float* __restrict__ outl)
{
    const int v = blockIdx.x * 64 + threadIdx.x;
    if (v >= VOCAB) return;
    float acc[BEAMS];
#pragma unroll
    for (int b = 0; b < BEAMS; ++b) acc[b] = 0.f;
#pragma unroll 8
    for (int d = 0; d < DIM; ++d) {
        float wv = wo[(size_t)d * VOCAB + v];            // coalesced across lanes
#pragma unroll
        for (int b = 0; b < BEAMS; ++b)
            acc[b] = fmaf(h[b * DIM + d], wv, acc[b]);   // h uniform -> s_load
    }
#pragma unroll
    for (int b = 0; b < BEAMS; ++b)
        outl[(size_t)b * VOCAB + v] = acc[b];
}

// ------------------------------------------------------------- launch -------
extern "C" void kernel_launch(void* const* d_in, const int* in_sizes, int n_in,
                              void* d_out, int out_size, void* d_ws, size_t ws_size,
                              hipStream_t stream) {
    const float* logprobs0 = (const float*)d_in[0];
    const float* h0  = (const float*)d_in[1];
    const float* emb = (const float*)d_in[2];
    const float* wx  = (const float*)d_in[3];
    const float* wh  = (const float*)d_in[4];
    const float* wo  = (const float*)d_in[5];
    float* out = (float*)d_out;

    float* wsf    = (float*)d_ws;
    float* logits = wsf;                         // BEAMS*VOCAB = 502570 floats
    float* pvals  = logits + 502592;             // 1600
    int*   pidx   = (int*)(pvals + 1600);        // 1600
    float* pmax   = (float*)(pidx + 1600);       // 160
    float* psum   = pmax + 160;                  // 160
    int*   toks   = (int*)(psum + 160);          // 16
    int*   qsel   = toks + 16;                   // 16
    float* hA     = (float*)(qsel + 16);         // 10240
    float* hB     = hA + BEAMS * DIM;            // 10240

    for (int t = 0; t < TSTEPS; ++t) {
        const float* lsrc = (t == 0) ? logprobs0 : logits;
        k_topk_partial<<<BEAMS * NBLK, K1T, 0, stream>>>(lsrc, pvals, pidx, pmax, psum);
        k_select_update<<<1, 640, 0, stream>>>(pvals, pidx, pmax, psum, out, toks, qsel, t);
        if (t < TSTEPS - 1) {
            const float* hprev = (t == 0) ? h0 : ((t & 1) ? hA : hB);
            float* hcur = (t & 1) ? hB : hA;
            k_rnn<<<BEAMS * 4, 256, 0, stream>>>(emb, wx, wh, hprev, toks, qsel, hcur);
            k_logits<<<(VOCAB + 63) / 64, 64, 0, stream>>>(hcur, wo, logits);
        }
    }
}